// Round 1
// baseline (634.480 us; speedup 1.0000x reference)
//
#include <hip/hip_runtime.h>
#include <hip/hip_bf16.h>
#include <math.h>

#define N_USERS 16384
#define N_ITEMS 4096
#define DD      64
#define BB      2048
#define EPSV    1e-8f

// ---------------- Kernel 1: per-user row stats (avg rating, emb norm) ------
__global__ __launch_bounds__(256) void k_rowstats(
    const float* __restrict__ R, const float* __restrict__ E,
    float* __restrict__ avg, float* __restrict__ mag)
{
    const int n = blockIdx.x;
    const int tid = threadIdx.x;
    const float4* row = (const float4*)(R + (size_t)n * N_ITEMS);

    float sum = 0.f, cnt = 0.f;
#pragma unroll
    for (int j = 0; j < 4; ++j) {
        float4 v = row[tid + j * 256];
        if (v.x == v.x) { sum += v.x; cnt += 1.f; }
        if (v.y == v.y) { sum += v.y; cnt += 1.f; }
        if (v.z == v.z) { sum += v.z; cnt += 1.f; }
        if (v.w == v.w) { sum += v.w; cnt += 1.f; }
    }

    // wave reduce (64 lanes) then cross-wave via LDS
    const int lane = tid & 63;
    const int wid  = tid >> 6;
#pragma unroll
    for (int o = 32; o > 0; o >>= 1) {
        sum += __shfl_down(sum, o);
        cnt += __shfl_down(cnt, o);
    }
    __shared__ float s_sum[4], s_cnt[4];
    if (lane == 0) { s_sum[wid] = sum; s_cnt[wid] = cnt; }
    __syncthreads();
    if (tid == 0) {
        float S = s_sum[0] + s_sum[1] + s_sum[2] + s_sum[3];
        float C = s_cnt[0] + s_cnt[1] + s_cnt[2] + s_cnt[3];
        avg[n] = (C > 0.f) ? (S / C) : 0.f;
    }

    // embedding norm: 16 lanes of wave 0, 4 floats each
    if (tid < 16) {
        float4 e = ((const float4*)(E + (size_t)n * DD))[tid];
        float ss = e.x * e.x + e.y * e.y + e.z * e.z + e.w * e.w;
#pragma unroll
        for (int o = 8; o > 0; o >>= 1) ss += __shfl_down(ss, o, 16);
        if (tid == 0) mag[n] = sqrtf(ss);
    }
}

// ---------------- Kernel 2: pairwise accumulate over an n-chunk ------------
#define NC 128   // users per block (grid.y = N_USERS / NC)

__global__ __launch_bounds__(256) void k_accum(
    const float* __restrict__ R, const float* __restrict__ E,
    const int* __restrict__ uidx, const int* __restrict__ iidx,
    const float* __restrict__ avg, const float* __restrict__ mag,
    float* __restrict__ num, float* __restrict__ den)
{
    const int b  = blockIdx.x * 256 + threadIdx.x;   // thread owns query b
    const int n0 = blockIdx.y * NC;

    const int ub = uidx[b];
    const int ib = iidx[b];
    const float mu = mag[ub];

    // u_b held entirely in registers (64 VGPRs)
    float4 u[16];
    const float4* ur = (const float4*)(E + (size_t)ub * DD);
#pragma unroll
    for (int k = 0; k < 16; ++k) u[k] = ur[k];

    float fnum = 0.f, fden = 0.f;

    for (int i = 0; i < NC; ++i) {
        const int n = __builtin_amdgcn_readfirstlane(n0 + i);  // wave-uniform
        const float4* vr = (const float4*)(E + (size_t)n * DD);
        const float a  = avg[n];
        const float mv = mag[n];
        const float r  = R[(size_t)n * N_ITEMS + ib];          // per-lane gather

        float d0 = 0.f, d1 = 0.f, d2 = 0.f, d3 = 0.f;
#pragma unroll
        for (int k = 0; k < 16; k += 4) {
            float4 v0 = vr[k + 0], v1 = vr[k + 1], v2 = vr[k + 2], v3 = vr[k + 3];
            d0 += u[k + 0].x * v0.x + u[k + 0].y * v0.y + u[k + 0].z * v0.z + u[k + 0].w * v0.w;
            d1 += u[k + 1].x * v1.x + u[k + 1].y * v1.y + u[k + 1].z * v1.z + u[k + 1].w * v1.w;
            d2 += u[k + 2].x * v2.x + u[k + 2].y * v2.y + u[k + 2].z * v2.z + u[k + 2].w * v2.w;
            d3 += u[k + 3].x * v3.x + u[k + 3].y * v3.y + u[k + 3].z * v3.z + u[k + 3].w * v3.w;
        }
        const float dot = (d0 + d1) + (d2 + d3);

        const bool valid = (r == r) && (n != ub);
        const float sim  = dot * __builtin_amdgcn_rcpf(mu * mv + EPSV);
        const float sm   = valid ? sim : 0.f;
        fnum += (valid ? (r - a) : 0.f) * sm;
        fden += fabsf(sm);
    }

    atomicAdd(&num[b], fnum);
    atomicAdd(&den[b], fden);
}

// ---------------- Kernel 3: finalize --------------------------------------
__global__ __launch_bounds__(256) void k_final(
    const int* __restrict__ uidx, const float* __restrict__ avg,
    const float* __restrict__ num, const float* __restrict__ den,
    float* __restrict__ out)
{
    const int b = blockIdx.x * 256 + threadIdx.x;
    const float au = avg[uidx[b]];
    const float d  = den[b];
    out[b] = (d == 0.f) ? au : (au + num[b] / d);
}

// ---------------- Launch ----------------------------------------------------
extern "C" void kernel_launch(void* const* d_in, const int* in_sizes, int n_in,
                              void* d_out, int out_size, void* d_ws, size_t ws_size,
                              hipStream_t stream)
{
    const float* R    = (const float*)d_in[0];
    const float* E    = (const float*)d_in[1];
    const int*   uidx = (const int*)d_in[2];
    const int*   iidx = (const int*)d_in[3];
    float* out = (float*)d_out;

    // workspace layout (floats): avg[16384] | mag[16384] | num[2048] | den[2048]
    float* avg = (float*)d_ws;
    float* mag = avg + N_USERS;
    float* num = mag + N_USERS;
    float* den = num + BB;

    // zero num/den (ws is poisoned before every launch)
    hipMemsetAsync(num, 0, 2 * BB * sizeof(float), stream);

    k_rowstats<<<N_USERS, 256, 0, stream>>>(R, E, avg, mag);

    dim3 g2(BB / 256, N_USERS / NC);
    k_accum<<<g2, 256, 0, stream>>>(R, E, uidx, iidx, avg, mag, num, den);

    k_final<<<BB / 256, 256, 0, stream>>>(uidx, avg, num, den, out);
}

// Round 3
// 588.792 us; speedup vs baseline: 1.0776x; 1.0776x over previous
//
#include <hip/hip_runtime.h>
#include <hip/hip_bf16.h>
#include <math.h>

#define N_USERS 16384
#define N_ITEMS 4096
#define DD      64
#define BB      2048
#define EPSV    1e-8f
#define RPB     8     // rows per block in k_rowgather
#define NC      128   // users per block-chunk in k_accum

// ============ Fused pass 1: row stats + item-gather into dense G[n][b] =====
__global__ __launch_bounds__(256) void k_rowgather(
    const float* __restrict__ R, const float* __restrict__ E,
    const int* __restrict__ iidx,
    float* __restrict__ avg, float* __restrict__ mag, float* __restrict__ G)
{
    __shared__ float row[N_ITEMS];     // 16 KB
    __shared__ int   s_ii[BB];         // 8 KB
    __shared__ float s_sum[4], s_cnt[4];

    const int tid = threadIdx.x;
    for (int t = tid; t < BB; t += 256) s_ii[t] = iidx[t];

    const int n0 = blockIdx.x * RPB;
    for (int rr = 0; rr < RPB; ++rr) {
        const int n = n0 + rr;

        // stage row via registers (coalesced float4)
        const float4* rp = (const float4*)(R + (size_t)n * N_ITEMS);
        float4 vv[4];
#pragma unroll
        for (int j = 0; j < 4; ++j) vv[j] = rp[tid + j * 256];

        __syncthreads();               // prior iteration's LDS reads done
#pragma unroll
        for (int j = 0; j < 4; ++j) ((float4*)row)[tid + j * 256] = vv[j];

        // NaN-masked partial sums from registers
        float sum = 0.f, cnt = 0.f;
#pragma unroll
        for (int j = 0; j < 4; ++j) {
            if (vv[j].x == vv[j].x) { sum += vv[j].x; cnt += 1.f; }
            if (vv[j].y == vv[j].y) { sum += vv[j].y; cnt += 1.f; }
            if (vv[j].z == vv[j].z) { sum += vv[j].z; cnt += 1.f; }
            if (vv[j].w == vv[j].w) { sum += vv[j].w; cnt += 1.f; }
        }
        const int lane = tid & 63, wid = tid >> 6;
#pragma unroll
        for (int o = 32; o > 0; o >>= 1) {
            sum += __shfl_down(sum, o);
            cnt += __shfl_down(cnt, o);
        }
        if (lane == 0) { s_sum[wid] = sum; s_cnt[wid] = cnt; }

        // embedding norm for this row: wave 0, one float per lane
        if (tid < DD) {
            float e = E[(size_t)n * DD + tid];
            float ss = e * e;
#pragma unroll
            for (int o = 32; o > 0; o >>= 1) ss += __shfl_down(ss, o);
            if (tid == 0) mag[n] = sqrtf(ss);
        }

        __syncthreads();               // row + s_sum/s_cnt visible
        if (tid == 0) {
            float S = s_sum[0] + s_sum[1] + s_sum[2] + s_sum[3];
            float C = s_cnt[0] + s_cnt[1] + s_cnt[2] + s_cnt[3];
            avg[n] = (C > 0.f) ? (S / C) : 0.f;
        }

        // gather all B items from LDS, write dense coalesced row G[n][:]
        float* Gn = G + (size_t)n * BB;
        for (int b = tid; b < BB; b += 256) Gn[b] = row[s_ii[b]];
    }
}

// ============ Pass 2: pairwise accumulate, dense coalesced G reads =========
__global__ __launch_bounds__(256) void k_accum2(
    const float* __restrict__ G, const float* __restrict__ E,
    const int* __restrict__ uidx,
    const float* __restrict__ avg, const float* __restrict__ mag,
    float* __restrict__ num, float* __restrict__ den)
{
    const int b  = blockIdx.x * 256 + threadIdx.x;   // thread owns query b
    const int n0 = blockIdx.y * NC;

    const int ub = uidx[b];
    const float mu = mag[ub];

    float4 u[16];
    const float4* ur = (const float4*)(E + (size_t)ub * DD);
#pragma unroll
    for (int k = 0; k < 16; ++k) u[k] = ur[k];

    float fnum = 0.f, fden = 0.f;

    for (int i = 0; i < NC; ++i) {
        const int n = __builtin_amdgcn_readfirstlane(n0 + i);  // wave-uniform
        const float4* vr = (const float4*)(E + (size_t)n * DD);
        const float a  = avg[n];
        const float mv = mag[n];
        const float r  = G[(size_t)n * BB + b];                // coalesced

        float d0 = 0.f, d1 = 0.f, d2 = 0.f, d3 = 0.f;
#pragma unroll
        for (int k = 0; k < 16; k += 4) {
            float4 v0 = vr[k + 0], v1 = vr[k + 1], v2 = vr[k + 2], v3 = vr[k + 3];
            d0 += u[k + 0].x * v0.x + u[k + 0].y * v0.y + u[k + 0].z * v0.z + u[k + 0].w * v0.w;
            d1 += u[k + 1].x * v1.x + u[k + 1].y * v1.y + u[k + 1].z * v1.z + u[k + 1].w * v1.w;
            d2 += u[k + 2].x * v2.x + u[k + 2].y * v2.y + u[k + 2].z * v2.z + u[k + 2].w * v2.w;
            d3 += u[k + 3].x * v3.x + u[k + 3].y * v3.y + u[k + 3].z * v3.z + u[k + 3].w * v3.w;
        }
        const float dot = (d0 + d1) + (d2 + d3);

        const bool valid = (r == r) && (n != ub);
        const float sim  = dot * __builtin_amdgcn_rcpf(mu * mv + EPSV);
        const float sm   = valid ? sim : 0.f;
        fnum += (valid ? (r - a) : 0.f) * sm;
        fden += fabsf(sm);
    }

    atomicAdd(&num[b], fnum);
    atomicAdd(&den[b], fden);
}

// ============ Fallback pass 1/2 (round-1 versions, used if ws too small) ===
__global__ __launch_bounds__(256) void k_rowstats_fb(
    const float* __restrict__ R, const float* __restrict__ E,
    float* __restrict__ avg, float* __restrict__ mag)
{
    const int n = blockIdx.x;
    const int tid = threadIdx.x;
    const float4* row = (const float4*)(R + (size_t)n * N_ITEMS);

    float sum = 0.f, cnt = 0.f;
#pragma unroll
    for (int j = 0; j < 4; ++j) {
        float4 v = row[tid + j * 256];
        if (v.x == v.x) { sum += v.x; cnt += 1.f; }
        if (v.y == v.y) { sum += v.y; cnt += 1.f; }
        if (v.z == v.z) { sum += v.z; cnt += 1.f; }
        if (v.w == v.w) { sum += v.w; cnt += 1.f; }
    }
    const int lane = tid & 63, wid = tid >> 6;
#pragma unroll
    for (int o = 32; o > 0; o >>= 1) {
        sum += __shfl_down(sum, o);
        cnt += __shfl_down(cnt, o);
    }
    __shared__ float s_sum[4], s_cnt[4];
    if (lane == 0) { s_sum[wid] = sum; s_cnt[wid] = cnt; }
    __syncthreads();
    if (tid == 0) {
        float S = s_sum[0] + s_sum[1] + s_sum[2] + s_sum[3];
        float C = s_cnt[0] + s_cnt[1] + s_cnt[2] + s_cnt[3];
        avg[n] = (C > 0.f) ? (S / C) : 0.f;
    }
    if (tid < 16) {
        float4 e = ((const float4*)(E + (size_t)n * DD))[tid];
        float ss = e.x * e.x + e.y * e.y + e.z * e.z + e.w * e.w;
#pragma unroll
        for (int o = 8; o > 0; o >>= 1) ss += __shfl_down(ss, o, 16);
        if (tid == 0) mag[n] = sqrtf(ss);
    }
}

__global__ __launch_bounds__(256) void k_accum_fb(
    const float* __restrict__ R, const float* __restrict__ E,
    const int* __restrict__ uidx, const int* __restrict__ iidx,
    const float* __restrict__ avg, const float* __restrict__ mag,
    float* __restrict__ num, float* __restrict__ den)
{
    const int b  = blockIdx.x * 256 + threadIdx.x;
    const int n0 = blockIdx.y * NC;
    const int ub = uidx[b];
    const int ib = iidx[b];
    const float mu = mag[ub];

    float4 u[16];
    const float4* ur = (const float4*)(E + (size_t)ub * DD);
#pragma unroll
    for (int k = 0; k < 16; ++k) u[k] = ur[k];

    float fnum = 0.f, fden = 0.f;
    for (int i = 0; i < NC; ++i) {
        const int n = __builtin_amdgcn_readfirstlane(n0 + i);
        const float4* vr = (const float4*)(E + (size_t)n * DD);
        const float a  = avg[n];
        const float mv = mag[n];
        const float r  = R[(size_t)n * N_ITEMS + ib];

        float d0 = 0.f, d1 = 0.f, d2 = 0.f, d3 = 0.f;
#pragma unroll
        for (int k = 0; k < 16; k += 4) {
            float4 v0 = vr[k + 0], v1 = vr[k + 1], v2 = vr[k + 2], v3 = vr[k + 3];
            d0 += u[k + 0].x * v0.x + u[k + 0].y * v0.y + u[k + 0].z * v0.z + u[k + 0].w * v0.w;
            d1 += u[k + 1].x * v1.x + u[k + 1].y * v1.y + u[k + 1].z * v1.z + u[k + 1].w * v1.w;
            d2 += u[k + 2].x * v2.x + u[k + 2].y * v2.y + u[k + 2].z * v2.z + u[k + 2].w * v2.w;
            d3 += u[k + 3].x * v3.x + u[k + 3].y * v3.y + u[k + 3].z * v3.z + u[k + 3].w * v3.w;
        }
        const float dot = (d0 + d1) + (d2 + d3);

        const bool valid = (r == r) && (n != ub);
        const float sim  = dot * __builtin_amdgcn_rcpf(mu * mv + EPSV);
        const float sm   = valid ? sim : 0.f;
        fnum += (valid ? (r - a) : 0.f) * sm;
        fden += fabsf(sm);
    }
    atomicAdd(&num[b], fnum);
    atomicAdd(&den[b], fden);
}

// ============ Finalize =====================================================
__global__ __launch_bounds__(256) void k_final(
    const int* __restrict__ uidx, const float* __restrict__ avg,
    const float* __restrict__ num, const float* __restrict__ den,
    float* __restrict__ out)
{
    const int b = blockIdx.x * 256 + threadIdx.x;
    const float au = avg[uidx[b]];
    const float d  = den[b];
    out[b] = (d == 0.f) ? au : (au + num[b] / d);
}

// ============ Launch =======================================================
extern "C" void kernel_launch(void* const* d_in, const int* in_sizes, int n_in,
                              void* d_out, int out_size, void* d_ws, size_t ws_size,
                              hipStream_t stream)
{
    const float* R    = (const float*)d_in[0];
    const float* E    = (const float*)d_in[1];
    const int*   uidx = (const int*)d_in[2];
    const int*   iidx = (const int*)d_in[3];
    float* out = (float*)d_out;

    // ws layout (floats): avg[16384] | mag[16384] | num[2048] | den[2048] | G[16384*2048]
    float* avg = (float*)d_ws;
    float* mag = avg + N_USERS;
    float* num = mag + N_USERS;
    float* den = num + BB;
    float* G   = den + BB;

    const size_t need = ((size_t)(2 * N_USERS + 2 * BB) + (size_t)N_USERS * BB) * sizeof(float);

    hipMemsetAsync(num, 0, 2 * BB * sizeof(float), stream);

    if (ws_size >= need) {
        k_rowgather<<<N_USERS / RPB, 256, 0, stream>>>(R, E, iidx, avg, mag, G);
        dim3 g2(BB / 256, N_USERS / NC);
        k_accum2<<<g2, 256, 0, stream>>>(G, E, uidx, avg, mag, num, den);
    } else {
        k_rowstats_fb<<<N_USERS, 256, 0, stream>>>(R, E, avg, mag);
        dim3 g2(BB / 256, N_USERS / NC);
        k_accum_fb<<<g2, 256, 0, stream>>>(R, E, uidx, iidx, avg, mag, num, den);
    }

    k_final<<<BB / 256, 256, 0, stream>>>(uidx, avg, num, den, out);
}

// Round 4
// 463.199 us; speedup vs baseline: 1.3698x; 1.2711x over previous
//
#include <hip/hip_runtime.h>
#include <math.h>

#define NU   16384
#define NI   4096
#define DDIM 64
#define BB   2048

typedef unsigned short ushort_t;
typedef __attribute__((ext_vector_type(8))) short short8;
typedef __attribute__((ext_vector_type(4))) float f32x4;

// fp32 -> bf16, round-nearest-even; preserves quiet NaN (inputs bounded, no overflow).
static __device__ __forceinline__ unsigned short f2bf(float f) {
    union { float f; unsigned int u; } v; v.f = f;
    unsigned int u = v.u + 0x7FFFu + ((v.u >> 16) & 1u);
    return (unsigned short)(u >> 16);
}
static __device__ __forceinline__ float bf2f(unsigned short h) {
    union { unsigned int u; float f; } v; v.u = ((unsigned int)h) << 16;
    return v.f;
}

// ===== k_qprep: per-query b: Ubf[b][k]=bf16(E[uidx[b]][k]); qinfo={ub, 1/|u|} =====
__global__ __launch_bounds__(256) void k_qprep(
    const float* __restrict__ E, const int* __restrict__ uidx,
    ushort_t* __restrict__ Ubf, int2* __restrict__ qinfo)
{
    const int lane = threadIdx.x & 63;
    const int b = blockIdx.x * 4 + (threadIdx.x >> 6);
    const int ub = uidx[b];
    const float e = E[(size_t)ub * DDIM + lane];
    float ss = e * e;
#pragma unroll
    for (int o = 32; o > 0; o >>= 1) ss += __shfl_xor(ss, o);
    Ubf[b * DDIM + lane] = f2bf(e);
    if (lane == 0) qinfo[b] = make_int2(ub, __float_as_int(rsqrtf(ss)));
}

// ===== k_rowgather: one wave per user-row, barrier-free row loop.
// Streams R once; computes avg[n], inv_mag[n] (-> ani), gathers item column
// through per-wave LDS row, writes dense bf16 Gbf[n][b]. =====
__global__ __launch_bounds__(256) void k_rowgather(
    const float* __restrict__ R, const float* __restrict__ E,
    const int* __restrict__ iidx,
    float2* __restrict__ ani, ushort_t* __restrict__ Gbf)
{
    __shared__ ushort_t rowb[4][NI];   // 32 KB: 8 KB per wave
    __shared__ ushort_t s_ii[BB];      // 4 KB
    const int tid  = threadIdx.x;
    const int lane = tid & 63;
    const int wid  = tid >> 6;

    for (int t = tid; t < BB; t += 256) s_ii[t] = (ushort_t)iidx[t];
    __syncthreads();   // the only block barrier

    const int gw = blockIdx.x * 4 + wid;
#pragma unroll 1
    for (int rr = 0; rr < 4; ++rr) {
        const int n = gw * 4 + rr;
        const float4* R4 = (const float4*)(R + (size_t)n * NI);
        float sum = 0.f, cnt = 0.f;
#pragma unroll
        for (int g = 0; g < 4; ++g) {
            float4 vv[4];
#pragma unroll
            for (int j = 0; j < 4; ++j) vv[j] = R4[(g * 4 + j) * 64 + lane];
#pragma unroll
            for (int j = 0; j < 4; ++j) {
                const float4 v = vv[j];
                if (v.x == v.x) { sum += v.x; cnt += 1.f; }
                if (v.y == v.y) { sum += v.y; cnt += 1.f; }
                if (v.z == v.z) { sum += v.z; cnt += 1.f; }
                if (v.w == v.w) { sum += v.w; cnt += 1.f; }
                ushort4 h;
                h.x = f2bf(v.x); h.y = f2bf(v.y); h.z = f2bf(v.z); h.w = f2bf(v.w);
                *(ushort4*)&rowb[wid][((g * 4 + j) * 64 + lane) * 4] = h;
            }
        }
        // embedding norm for this row
        const float e = E[(size_t)n * DDIM + lane];
        float ss = e * e;
#pragma unroll
        for (int o = 32; o > 0; o >>= 1) ss += __shfl_xor(ss, o);
        // row sum/cnt reduce
#pragma unroll
        for (int o = 32; o > 0; o >>= 1) {
            sum += __shfl_xor(sum, o);
            cnt += __shfl_xor(cnt, o);
        }
        if (lane == 0) {
            const float avg = (cnt > 0.f) ? (sum / cnt) : 0.f;
            ani[n] = make_float2(avg, rsqrtf(ss));
        }
        // wave-internal LDS RAW fence (same wave: lgkmcnt suffices, no barrier)
        asm volatile("s_waitcnt lgkmcnt(0)" ::: "memory");
        // gather full item column from LDS, write dense coalesced bf16 row
        ushort_t* Gn = Gbf + (size_t)n * BB;
#pragma unroll
        for (int it = 0; it < 32; ++it) {
            const int b = it * 64 + lane;
            Gn[b] = rowb[wid][s_ii[b]];
        }
    }
}

// ===== k_accum: MFMA 16x16x32 bf16. Block = 16-row n-tile x all 2048 b.
// Wave w handles b-tiles {j*4+w}. Per tile: 2 chained MFMA (K=64), masked
// epilogue, in-wave n-reduce, partials[block][b] (no atomics). =====
__global__ __launch_bounds__(256) void k_accum(
    const float* __restrict__ E, const ushort_t* __restrict__ Ubf,
    const ushort_t* __restrict__ Gbf, const float2* __restrict__ ani,
    const int2* __restrict__ qinfo, float2* __restrict__ partials)
{
    const int tid  = threadIdx.x;
    const int lane = tid & 63;
    const int w    = tid >> 6;
    const int lo   = lane & 15;
    const int hi   = lane >> 4;         // 0..3
    const int n0   = blockIdx.x * 16;

    // A fragments (E rows n0..n0+15, K=64), bf16-converted on the fly (once).
    short8 a[2];
#pragma unroll
    for (int kg = 0; kg < 2; ++kg) {
        const float* ep = E + (size_t)(n0 + lo) * DDIM + kg * 32 + hi * 8;
        const float4 e0 = *(const float4*)(ep);
        const float4 e1 = *(const float4*)(ep + 4);
        union { short8 v; ushort_t u[8]; } t;
        t.u[0] = f2bf(e0.x); t.u[1] = f2bf(e0.y); t.u[2] = f2bf(e0.z); t.u[3] = f2bf(e0.w);
        t.u[4] = f2bf(e1.x); t.u[5] = f2bf(e1.y); t.u[6] = f2bf(e1.z); t.u[7] = f2bf(e1.w);
        a[kg] = t.v;
    }
    // per-row (avg, inv_mag), hoisted across all b-tiles
    float2 anir[4];
#pragma unroll
    for (int r = 0; r < 4; ++r) anir[r] = ani[n0 + hi * 4 + r];

    float2* pout = partials + (size_t)blockIdx.x * BB;

#pragma unroll 1
    for (int j = 0; j < 32; ++j) {
        const int b0 = (j * 4 + w) * 16;
        const int2 q = qinfo[b0 + lo];
        const float inv_mu = __int_as_float(q.y);

        short8 bf[2];
#pragma unroll
        for (int kg = 0; kg < 2; ++kg)
            bf[kg] = *(const short8*)(Ubf + (size_t)(b0 + lo) * DDIM + kg * 32 + hi * 8);

        f32x4 c = {0.f, 0.f, 0.f, 0.f};
        c = __builtin_amdgcn_mfma_f32_16x16x32_bf16(a[0], bf[0], c, 0, 0, 0);
        c = __builtin_amdgcn_mfma_f32_16x16x32_bf16(a[1], bf[1], c, 0, 0, 0);

        float fnum = 0.f, fden = 0.f;
#pragma unroll
        for (int r = 0; r < 4; ++r) {
            const int nr = n0 + hi * 4 + r;                 // C/D row
            const float g = bf2f(Gbf[(size_t)nr * BB + b0 + lo]);
            const bool valid = (g == g) && (nr != q.x);
            const float s  = valid ? c[r] * (inv_mu * anir[r].y) : 0.f;
            const float gv = valid ? g : 0.f;
            fnum += (gv - anir[r].x) * s;                   // s==0 when invalid
            fden += fabsf(s);
        }
        // reduce over the 4 row-groups (lanes lo, lo+16, lo+32, lo+48)
        fnum += __shfl_xor(fnum, 16); fden += __shfl_xor(fden, 16);
        fnum += __shfl_xor(fnum, 32); fden += __shfl_xor(fden, 32);
        if (lane < 16) pout[b0 + lane] = make_float2(fnum, fden);
    }
}

// ===== k_final: reduce partials over 1024 n-tile blocks, finalize =====
__global__ __launch_bounds__(256) void k_final(
    const float2* __restrict__ partials, const float2* __restrict__ ani,
    const int2* __restrict__ qinfo, float* __restrict__ out)
{
    __shared__ float sn[8][32], sd[8][32];
    const int tid = threadIdx.x;
    const int bl  = tid & 31;
    const int ch  = tid >> 5;
    const int b   = blockIdx.x * 32 + bl;
    float n = 0.f, d = 0.f;
    for (int blk = ch; blk < NU / 16; blk += 8) {
        const float2 p = partials[(size_t)blk * BB + b];
        n += p.x; d += p.y;
    }
    sn[ch][bl] = n; sd[ch][bl] = d;
    __syncthreads();
    if (tid < 32) {
        float N = 0.f, D = 0.f;
#pragma unroll
        for (int c2 = 0; c2 < 8; ++c2) { N += sn[c2][tid]; D += sd[c2][tid]; }
        const int bb = blockIdx.x * 32 + tid;
        const float au = ani[qinfo[bb].x].x;
        out[bb] = (D == 0.f) ? au : (au + N / D);
    }
}

// ===== Launch =====
extern "C" void kernel_launch(void* const* d_in, const int* in_sizes, int n_in,
                              void* d_out, int out_size, void* d_ws, size_t ws_size,
                              hipStream_t stream)
{
    const float* R    = (const float*)d_in[0];
    const float* E    = (const float*)d_in[1];
    const int*   uidx = (const int*)d_in[2];
    const int*   iidx = (const int*)d_in[3];
    float* out = (float*)d_out;

    // ws carve (all 256B-aligned): Gbf 64MiB | partials 16MiB | Ubf 256KB | ani 128KB | qinfo 16KB
    char* p = (char*)d_ws;
    ushort_t* Gbf   = (ushort_t*)p;              p += (size_t)NU * BB * 2;
    float2*   parts = (float2*)p;                p += (size_t)(NU / 16) * BB * 8;
    ushort_t* Ubf   = (ushort_t*)p;              p += (size_t)BB * DDIM * 2;
    float2*   ani   = (float2*)p;                p += (size_t)NU * 8;
    int2*     qinfo = (int2*)p;                  p += (size_t)BB * 8;

    k_qprep<<<BB / 4, 256, 0, stream>>>(E, uidx, Ubf, qinfo);
    k_rowgather<<<NU / 16, 256, 0, stream>>>(R, E, iidx, ani, Gbf);
    k_accum<<<NU / 16, 256, 0, stream>>>(E, Ubf, Gbf, ani, qinfo, parts);
    k_final<<<BB / 32, 256, 0, stream>>>(parts, ani, qinfo, out);
}

// Round 5
// 440.535 us; speedup vs baseline: 1.4402x; 1.0514x over previous
//
#include <hip/hip_runtime.h>
#include <math.h>

#define NU   16384
#define NI   4096
#define DDIM 64
#define BB   2048
#define GSTR 2052   // padded ushort stride: hi-groups land in disjoint 8-bank regions

typedef unsigned short u16;
typedef __attribute__((ext_vector_type(8))) short short8;
typedef __attribute__((ext_vector_type(4))) float f32x4;

// fp32 -> bf16 RNE; preserves NaN (ratings bounded, no overflow)
static __device__ __forceinline__ u16 f2bf(float f) {
    union { float f; unsigned int u; } v; v.f = f;
    unsigned int u = v.u + 0x7FFFu + ((v.u >> 16) & 1u);
    return (u16)(u >> 16);
}
static __device__ __forceinline__ float bf2f(u16 h) {
    union { unsigned int u; float f; } v; v.u = ((unsigned int)h) << 16;
    return v.f;
}

// ===== k_qprep: Ubf[b][k]=bf16(E[uidx[b]][k]); qinfo[b]={ub, 1/|u|} =====
__global__ __launch_bounds__(256) void k_qprep(
    const float* __restrict__ E, const int* __restrict__ uidx,
    u16* __restrict__ Ubf, int2* __restrict__ qinfo)
{
    const int lane = threadIdx.x & 63;
    const int b = blockIdx.x * 4 + (threadIdx.x >> 6);
    const int ub = uidx[b];
    const float e = E[(size_t)ub * DDIM + lane];
    float ss = e * e;
#pragma unroll
    for (int o = 32; o > 0; o >>= 1) ss += __shfl_xor(ss, o);
    Ubf[b * DDIM + lane] = f2bf(e);
    if (lane == 0) qinfo[b] = make_int2(ub, __float_as_int(rsqrtf(ss)));
}

// ===== k_fused: block = 16-row n-tile. Phase A streams R rows once (stats in
// regs, item-gather -> LDS g tile). Phase B: 2x MFMA per b-tile vs all 2048 b,
// epilogue from LDS, per-block partials (no atomics). Also exports avgAll[n]. =====
__global__ __launch_bounds__(256) void k_fused(
    const float* __restrict__ R, const float* __restrict__ E,
    const int* __restrict__ iidx, const u16* __restrict__ Ubf,
    const int2* __restrict__ qinfo, float2* __restrict__ partials,
    float* __restrict__ avgAll)
{
    __shared__ u16 s_ii[BB];          // 4 KB
    __shared__ u16 row[NI];           // 8 KB
    __shared__ u16 g[16][GSTR];       // 64.1 KB
    __shared__ float sAvg[16], sInv[16];
    __shared__ float redS[4], redC[4];

    const int tid  = threadIdx.x;
    const int lane = tid & 63;
    const int wid  = tid >> 6;
    const int n0   = blockIdx.x * 16;

    for (int t = tid; t < BB; t += 256) s_ii[t] = (u16)iidx[t];

    // embedding inv-norms: wave wid -> rows wid*4..+3
#pragma unroll
    for (int rs = 0; rs < 4; ++rs) {
        const int n = n0 + wid * 4 + rs;
        const float e = E[(size_t)n * DDIM + lane];
        float ss = e * e;
#pragma unroll
        for (int o = 32; o > 0; o >>= 1) ss += __shfl_xor(ss, o);
        if (lane == 0) sInv[wid * 4 + rs] = rsqrtf(ss);
    }

    // ---- Phase A ----
#pragma unroll 1
    for (int rr = 0; rr < 16; ++rr) {
        const int n = n0 + rr;
        const float4* R4 = (const float4*)(R + (size_t)n * NI);
        float4 vv[4];
#pragma unroll
        for (int j = 0; j < 4; ++j) vv[j] = R4[tid + j * 256];

        __syncthreads();   // prev gather done (iter 0: s_ii writes done)

        float sum = 0.f, cnt = 0.f;
#pragma unroll
        for (int j = 0; j < 4; ++j) {
            const float4 v = vv[j];
            if (v.x == v.x) { sum += v.x; cnt += 1.f; }
            if (v.y == v.y) { sum += v.y; cnt += 1.f; }
            if (v.z == v.z) { sum += v.z; cnt += 1.f; }
            if (v.w == v.w) { sum += v.w; cnt += 1.f; }
            ushort4 h;
            h.x = f2bf(v.x); h.y = f2bf(v.y); h.z = f2bf(v.z); h.w = f2bf(v.w);
            *(ushort4*)&row[(tid + j * 256) * 4] = h;
        }
#pragma unroll
        for (int o = 32; o > 0; o >>= 1) {
            sum += __shfl_xor(sum, o);
            cnt += __shfl_xor(cnt, o);
        }
        if (lane == 0) { redS[wid] = sum; redC[wid] = cnt; }

        __syncthreads();   // row + reds ready
        if (tid == 0) {
            const float S = redS[0] + redS[1] + redS[2] + redS[3];
            const float C = redC[0] + redC[1] + redC[2] + redC[3];
            const float a = (C > 0.f) ? (S / C) : 0.f;
            sAvg[rr] = a;
            avgAll[n] = a;           // export for k_final's avg_u lookup
        }
#pragma unroll
        for (int t = 0; t < 8; ++t) {
            const int b = tid + t * 256;
            g[rr][b] = row[s_ii[b]];
        }
    }
    __syncthreads();       // all g + sAvg + sInv ready

    // ---- Phase B ----
    const int lo = lane & 15;
    const int hi = lane >> 4;

    short8 a[2];
#pragma unroll
    for (int kg = 0; kg < 2; ++kg) {
        const float* ep = E + (size_t)(n0 + lo) * DDIM + kg * 32 + hi * 8;
        const float4 e0 = *(const float4*)(ep);
        const float4 e1 = *(const float4*)(ep + 4);
        union { short8 v; u16 u[8]; } t;
        t.u[0] = f2bf(e0.x); t.u[1] = f2bf(e0.y); t.u[2] = f2bf(e0.z); t.u[3] = f2bf(e0.w);
        t.u[4] = f2bf(e1.x); t.u[5] = f2bf(e1.y); t.u[6] = f2bf(e1.z); t.u[7] = f2bf(e1.w);
        a[kg] = t.v;
    }
    float avr[4], ivr[4];
#pragma unroll
    for (int r = 0; r < 4; ++r) { avr[r] = sAvg[hi * 4 + r]; ivr[r] = sInv[hi * 4 + r]; }

    float2* pout = partials + (size_t)blockIdx.x * BB;

#pragma unroll 1
    for (int j = 0; j < 32; ++j) {
        const int b0 = (j * 4 + wid) * 16;
        const int2 q = qinfo[b0 + lo];
        const float inv_mu = __int_as_float(q.y);

        const short8 bf0 = *(const short8*)(Ubf + (size_t)(b0 + lo) * DDIM + hi * 8);
        const short8 bf1 = *(const short8*)(Ubf + (size_t)(b0 + lo) * DDIM + 32 + hi * 8);

        f32x4 c = {0.f, 0.f, 0.f, 0.f};
        c = __builtin_amdgcn_mfma_f32_16x16x32_bf16(a[0], bf0, c, 0, 0, 0);
        c = __builtin_amdgcn_mfma_f32_16x16x32_bf16(a[1], bf1, c, 0, 0, 0);

        float fnum = 0.f, fden = 0.f;
#pragma unroll
        for (int r = 0; r < 4; ++r) {
            const int nr = n0 + hi * 4 + r;                  // C/D row (m89 mapping)
            const float gg = bf2f(g[hi * 4 + r][b0 + lo]);
            const bool valid = (gg == gg) && (nr != q.x);
            const float s  = valid ? c[r] * (inv_mu * ivr[r]) : 0.f;
            const float gv = valid ? gg : 0.f;
            fnum += (gv - avr[r]) * s;
            fden += fabsf(s);
        }
        fnum += __shfl_xor(fnum, 16); fden += __shfl_xor(fden, 16);
        fnum += __shfl_xor(fnum, 32); fden += __shfl_xor(fden, 32);
        if (lane < 16) pout[b0 + lane] = make_float2(fnum, fden);
    }
}

// ===== k_final: reduce partials, finalize =====
__global__ __launch_bounds__(256) void k_final(
    const float2* __restrict__ partials, const int2* __restrict__ qinfo,
    const float* __restrict__ avgAll, float* __restrict__ out)
{
    __shared__ float sn[8][32], sd[8][32];
    const int tid = threadIdx.x;
    const int bl  = tid & 31;
    const int ch  = tid >> 5;
    const int b   = blockIdx.x * 32 + bl;
    float n = 0.f, d = 0.f;
    for (int blk = ch; blk < NU / 16; blk += 8) {
        const float2 p = partials[(size_t)blk * BB + b];
        n += p.x; d += p.y;
    }
    sn[ch][bl] = n; sd[ch][bl] = d;
    __syncthreads();
    if (tid < 32) {
        float N = 0.f, D = 0.f;
#pragma unroll
        for (int c2 = 0; c2 < 8; ++c2) { N += sn[c2][tid]; D += sd[c2][tid]; }
        const int bb = blockIdx.x * 32 + tid;
        const float au = avgAll[qinfo[bb].x];
        out[bb] = (D == 0.f) ? au : (au + N / D);
    }
}

// ===== Launch =====
extern "C" void kernel_launch(void* const* d_in, const int* in_sizes, int n_in,
                              void* d_out, int out_size, void* d_ws, size_t ws_size,
                              hipStream_t stream)
{
    const float* R    = (const float*)d_in[0];
    const float* E    = (const float*)d_in[1];
    const int*   uidx = (const int*)d_in[2];
    const int*   iidx = (const int*)d_in[3];
    float* out = (float*)d_out;

    // ws carve: partials 16MiB | Ubf 256KB | qinfo 16KB | avgAll 64KB
    char* p = (char*)d_ws;
    float2* parts  = (float2*)p;  p += (size_t)(NU / 16) * BB * 8;
    u16*    Ubf    = (u16*)p;     p += (size_t)BB * DDIM * 2;
    int2*   qinfo  = (int2*)p;    p += (size_t)BB * 8;
    float*  avgAll = (float*)p;   p += (size_t)NU * 4;

    k_qprep<<<BB / 4, 256, 0, stream>>>(E, uidx, Ubf, qinfo);
    k_fused<<<NU / 16, 256, 0, stream>>>(R, E, iidx, Ubf, qinfo, parts, avgAll);
    k_final<<<BB / 32, 256, 0, stream>>>(parts, qinfo, avgAll, out);
}